// Round 1
// baseline (137.275 us; speedup 1.0000x reference)
//
#include <hip/hip_runtime.h>
#include <hip/hip_bf16.h>

// Problem: B=8, A=512, IN=OUT=1024, N_OPT=16, fp32 in/out.
// out[b,a,i] = sum_j (sum_n sp[b,n] W[n,i,j]) x[b,a,j] + sum_n sp[b,n] bias[n,i]
//
// Strategy: mix weights once (reads W 64MB exactly once), cast to bf16,
// then 8 batched MFMA GEMMs (C = X * Wm^T), bias folded into epilogue.

#define B_SZ 8
#define A_SZ 512
#define IN_F 1024
#define OUT_F 1024
#define N_OPT 16

typedef short short8 __attribute__((ext_vector_type(8)));
typedef float floatx4 __attribute__((ext_vector_type(4)));

__device__ __forceinline__ unsigned short f2bf(float f) {
    unsigned int u = __builtin_bit_cast(unsigned int, f);
    // round-to-nearest-even bf16 truncation (inputs are finite, no NaN guard needed)
    u += 0x7fffu + ((u >> 16) & 1u);
    return (unsigned short)(u >> 16);
}

#define GLOBAL_LOAD_LDS16(g, l)                                                    \
    __builtin_amdgcn_global_load_lds(                                              \
        (const __attribute__((address_space(1))) void*)(g),                        \
        (__attribute__((address_space(3))) void*)(l), 16, 0, 0)

// ---------------------------------------------------------------------------
// Kernel 1: prep.
//   blocks [0,1024):    weight mixing -> bf16 wm [8][1024][1024]
//   blocks [1024,5120): x fp32 -> bf16 xbf [8][512][1024]
//   blocks [5120,5128): bias mixing -> fp32 bmixed [8][1024]
// ---------------------------------------------------------------------------
__global__ __launch_bounds__(256) void selin_prep(
    const float* __restrict__ x, const float* __restrict__ sp,
    const float* __restrict__ weight, const float* __restrict__ bias,
    unsigned short* __restrict__ wm, unsigned short* __restrict__ xbf,
    float* __restrict__ bmixed)
{
    const int bid = blockIdx.x;
    const int tid = threadIdx.x;

    if (bid < 1024) {
        // --- weight mixing ---
        __shared__ float sps[B_SZ * N_OPT];
        if (tid < B_SZ * N_OPT) sps[tid] = sp[tid];
        __syncthreads();
        const int e4 = bid * 256 + tid;              // float4 index into 1024x1024
        const float4* w4 = (const float4*)weight;
        float4 w[N_OPT];
#pragma unroll
        for (int n = 0; n < N_OPT; n++)
            w[n] = w4[(size_t)n * (IN_F * OUT_F / 4) + e4];
#pragma unroll
        for (int b = 0; b < B_SZ; b++) {
            float ax = 0.f, ay = 0.f, az = 0.f, aw = 0.f;
#pragma unroll
            for (int n = 0; n < N_OPT; n++) {
                float s = sps[b * N_OPT + n];
                ax += s * w[n].x; ay += s * w[n].y;
                az += s * w[n].z; aw += s * w[n].w;
            }
            ushort4 o = make_ushort4(f2bf(ax), f2bf(ay), f2bf(az), f2bf(aw));
            ((ushort4*)wm)[(size_t)b * (IN_F * OUT_F / 4) + e4] = o;
        }
    } else if (bid < 5120) {
        // --- x conversion ---
        const int idx = (bid - 1024) * 256 + tid;    // float4 index, 1M total
        float4 v = ((const float4*)x)[idx];
        ((ushort4*)xbf)[idx] = make_ushort4(f2bf(v.x), f2bf(v.y), f2bf(v.z), f2bf(v.w));
    } else {
        // --- bias mixing ---
        __shared__ float sps[B_SZ * N_OPT];
        if (tid < B_SZ * N_OPT) sps[tid] = sp[tid];
        __syncthreads();
        const int idx = (bid - 5120) * 256 + tid;    // 0..2047 (float4 over 8x1024)
        const int b = idx >> 8, i4 = idx & 255;
        const float4* bias4 = (const float4*)bias;
        float ax = 0.f, ay = 0.f, az = 0.f, aw = 0.f;
#pragma unroll
        for (int n = 0; n < N_OPT; n++) {
            float s = sps[b * N_OPT + n];
            float4 v = bias4[n * 256 + i4];
            ax += s * v.x; ay += s * v.y; az += s * v.z; aw += s * v.w;
        }
        ((float4*)bmixed)[idx] = make_float4(ax, ay, az, aw);
    }
}

// ---------------------------------------------------------------------------
// Kernel 2: batched GEMM, C[b] = X[b] (512x1024) * Wm[b]^T (1024x1024) + bias.
// 128x128 tile, BK=32, 4 waves, each wave 64x64 via 4x4 grid of 16x16x32 MFMA.
// Grid: 8 batches * 4 m-blocks * 8 n-blocks = 256 blocks.
// ---------------------------------------------------------------------------
__global__ __launch_bounds__(256) void selin_gemm(
    const unsigned short* __restrict__ xbf, const unsigned short* __restrict__ wm,
    const float* __restrict__ bmixed, float* __restrict__ out)
{
    __shared__ __align__(16) unsigned short As[128 * 32];
    __shared__ __align__(16) unsigned short Bs[128 * 32];

    const int tid = threadIdx.x;
    const int bid = blockIdx.x;
    const int b   = bid >> 5;
    const int mb  = (bid >> 3) & 3;   // m block (A rows of x)
    const int nb  = bid & 7;          // n block (out features)
    const int m0  = mb * 128, n0 = nb * 128;

    const unsigned short* Ag = xbf + ((size_t)b * A_SZ  + m0) * IN_F;
    const unsigned short* Bg = wm  + ((size_t)b * OUT_F + n0) * IN_F;

    // staging: 128x32 bf16 tile = 8KB = 512 chunks of 16B; 256 threads x 2 chunks
    const int c0 = tid, c1 = tid + 256;
    const int goff0 = (c0 >> 2) * IN_F + (c0 & 3) * 8;  // + k0 at use
    const int goff1 = (c1 >> 2) * IN_F + (c1 & 3) * 8;

    const int lane = tid & 63;
    const int wv   = tid >> 6;
    const int wmi  = wv >> 1, wni = wv & 1;   // 2x2 wave grid
    const int lm   = lane & 15, kq = lane >> 4;

    floatx4 acc[4][4];
#pragma unroll
    for (int i = 0; i < 4; i++)
#pragma unroll
        for (int j = 0; j < 4; j++)
            acc[i][j] = (floatx4){0.f, 0.f, 0.f, 0.f};

    for (int k0 = 0; k0 < IN_F; k0 += 32) {
        GLOBAL_LOAD_LDS16(Ag + goff0 + k0, &As[c0 * 8]);
        GLOBAL_LOAD_LDS16(Ag + goff1 + k0, &As[c1 * 8]);
        GLOBAL_LOAD_LDS16(Bg + goff0 + k0, &Bs[c0 * 8]);
        GLOBAL_LOAD_LDS16(Bg + goff1 + k0, &Bs[c1 * 8]);
        __syncthreads();   // drains vmcnt -> LDS tiles complete

        short8 a[4], bb[4];
#pragma unroll
        for (int mi = 0; mi < 4; mi++)
            a[mi] = *(const short8*)&As[(wmi * 64 + mi * 16 + lm) * 32 + kq * 8];
#pragma unroll
        for (int ni = 0; ni < 4; ni++)
            bb[ni] = *(const short8*)&Bs[(wni * 64 + ni * 16 + lm) * 32 + kq * 8];

#pragma unroll
        for (int mi = 0; mi < 4; mi++)
#pragma unroll
            for (int ni = 0; ni < 4; ni++)
                acc[mi][ni] = __builtin_amdgcn_mfma_f32_16x16x32_bf16(
                    a[mi], bb[ni], acc[mi][ni], 0, 0, 0);
        __syncthreads();   // all reads done before next staging overwrites LDS
    }

    // epilogue: C/D layout col=lane&15, row=(lane>>4)*4+reg
#pragma unroll
    for (int ni = 0; ni < 4; ni++) {
        const int gcol = n0 + wni * 64 + ni * 16 + lm;
        const float bv = bmixed[b * OUT_F + gcol];
#pragma unroll
        for (int mi = 0; mi < 4; mi++) {
            const int grow = m0 + wmi * 64 + mi * 16 + kq * 4;
            float* op = out + ((size_t)b * A_SZ + grow) * OUT_F + gcol;
#pragma unroll
            for (int r = 0; r < 4; r++)
                op[(size_t)r * OUT_F] = acc[mi][ni][r] + bv;
        }
    }
}

extern "C" void kernel_launch(void* const* d_in, const int* in_sizes, int n_in,
                              void* d_out, int out_size, void* d_ws, size_t ws_size,
                              hipStream_t stream) {
    const float* x      = (const float*)d_in[0];  // [8,512,1024]
    const float* sp     = (const float*)d_in[1];  // [8,16]
    const float* weight = (const float*)d_in[2];  // [16,1024,1024]
    const float* bias   = (const float*)d_in[3];  // [16,1024]
    float* out = (float*)d_out;                   // [8,512,1024]

    // workspace layout: wm bf16 16MB | xbf bf16 8MB | bmixed fp32 32KB
    unsigned short* wm  = (unsigned short*)d_ws;
    unsigned short* xbf = wm + (size_t)B_SZ * OUT_F * IN_F;
    float* bmixed       = (float*)(xbf + (size_t)B_SZ * A_SZ * IN_F);

    selin_prep<<<5128, 256, 0, stream>>>(x, sp, weight, bias, wm, xbf, bmixed);
    selin_gemm<<<256, 256, 0, stream>>>(xbf, wm, bmixed, out);
}

// Round 2
// 136.992 us; speedup vs baseline: 1.0021x; 1.0021x over previous
//
#include <hip/hip_runtime.h>
#include <hip/hip_bf16.h>

// Problem: B=8, A=512, IN=OUT=1024, N_OPT=16, fp32 in/out.
// out[b,a,i] = sum_j (sum_n sp[b,n] W[n,i,j]) x[b,a,j] + sum_n sp[b,n] bias[n,i]
//
// Strategy: mix weights once (reads W 64MB exactly once), cast to bf16,
// then 8 batched MFMA GEMMs (C = X * Wm^T), bias folded into epilogue.
//
// R1->R2: gemm retiled 128x128/256blk (1 wave/SIMD, latency-exposed) ->
// 64x128/512blk (2 blocks/CU, 2 waves/SIMD) for latency hiding.

#define B_SZ 8
#define A_SZ 512
#define IN_F 1024
#define OUT_F 1024
#define N_OPT 16

typedef short short8 __attribute__((ext_vector_type(8)));
typedef float floatx4 __attribute__((ext_vector_type(4)));

__device__ __forceinline__ unsigned short f2bf(float f) {
    unsigned int u = __builtin_bit_cast(unsigned int, f);
    u += 0x7fffu + ((u >> 16) & 1u);   // RNE; inputs finite
    return (unsigned short)(u >> 16);
}

#define GLOBAL_LOAD_LDS16(g, l)                                                    \
    __builtin_amdgcn_global_load_lds(                                              \
        (const __attribute__((address_space(1))) void*)(g),                        \
        (__attribute__((address_space(3))) void*)(l), 16, 0, 0)

// ---------------------------------------------------------------------------
// Kernel 1: prep.
//   blocks [0,1024):    weight mixing -> bf16 wm [8][1024][1024]
//   blocks [1024,5120): x fp32 -> bf16 xbf [8][512][1024]
//   blocks [5120,5128): bias mixing -> fp32 bmixed [8][1024]
// ---------------------------------------------------------------------------
__global__ __launch_bounds__(256) void selin_prep(
    const float* __restrict__ x, const float* __restrict__ sp,
    const float* __restrict__ weight, const float* __restrict__ bias,
    unsigned short* __restrict__ wm, unsigned short* __restrict__ xbf,
    float* __restrict__ bmixed)
{
    const int bid = blockIdx.x;
    const int tid = threadIdx.x;

    if (bid < 1024) {
        __shared__ float sps[B_SZ * N_OPT];
        if (tid < B_SZ * N_OPT) sps[tid] = sp[tid];
        __syncthreads();
        const int e4 = bid * 256 + tid;              // float4 index into 1024x1024
        const float4* w4 = (const float4*)weight;
        float4 w[N_OPT];
#pragma unroll
        for (int n = 0; n < N_OPT; n++)
            w[n] = w4[(size_t)n * (IN_F * OUT_F / 4) + e4];
#pragma unroll
        for (int b = 0; b < B_SZ; b++) {
            float ax = 0.f, ay = 0.f, az = 0.f, aw = 0.f;
#pragma unroll
            for (int n = 0; n < N_OPT; n++) {
                float s = sps[b * N_OPT + n];
                ax += s * w[n].x; ay += s * w[n].y;
                az += s * w[n].z; aw += s * w[n].w;
            }
            ushort4 o = make_ushort4(f2bf(ax), f2bf(ay), f2bf(az), f2bf(aw));
            ((ushort4*)wm)[(size_t)b * (IN_F * OUT_F / 4) + e4] = o;
        }
    } else if (bid < 5120) {
        const int idx = (bid - 1024) * 256 + tid;    // float4 index, 1M total
        float4 v = ((const float4*)x)[idx];
        ((ushort4*)xbf)[idx] = make_ushort4(f2bf(v.x), f2bf(v.y), f2bf(v.z), f2bf(v.w));
    } else {
        __shared__ float sps[B_SZ * N_OPT];
        if (tid < B_SZ * N_OPT) sps[tid] = sp[tid];
        __syncthreads();
        const int idx = (bid - 5120) * 256 + tid;    // 0..2047 (float4 over 8x1024)
        const int b = idx >> 8, i4 = idx & 255;
        const float4* bias4 = (const float4*)bias;
        float ax = 0.f, ay = 0.f, az = 0.f, aw = 0.f;
#pragma unroll
        for (int n = 0; n < N_OPT; n++) {
            float s = sps[b * N_OPT + n];
            float4 v = bias4[n * 256 + i4];
            ax += s * v.x; ay += s * v.y; az += s * v.z; aw += s * v.w;
        }
        ((float4*)bmixed)[idx] = make_float4(ax, ay, az, aw);
    }
}

// ---------------------------------------------------------------------------
// Kernel 2: batched GEMM, C[b] = X[b] (512x1024) * Wm[b]^T (1024x1024) + bias.
// Tile 64(M) x 128(N), BK=32. 4 waves in 2x2; each wave 32x64 = 2x4 frags of
// 16x16x32 bf16 MFMA. Grid: 8 b * 8 mb * 8 nb = 512 blocks = 2 blocks/CU.
// ---------------------------------------------------------------------------
__global__ __launch_bounds__(256) void selin_gemm(
    const unsigned short* __restrict__ xbf, const unsigned short* __restrict__ wm,
    const float* __restrict__ bmixed, float* __restrict__ out)
{
    __shared__ __align__(16) unsigned short As[64 * 32];    // 4 KB
    __shared__ __align__(16) unsigned short Bs[128 * 32];   // 8 KB

    const int tid = threadIdx.x;
    const int bid = blockIdx.x;
    const int b   = bid >> 6;
    const int mb  = (bid >> 3) & 7;
    const int nb  = bid & 7;
    const int m0  = mb * 64, n0 = nb * 128;

    const unsigned short* Ag = xbf + ((size_t)b * A_SZ  + m0) * IN_F;
    const unsigned short* Bg = wm  + ((size_t)b * OUT_F + n0) * IN_F;

    // A: 64x32 = 256 16B-chunks (1/thread); B: 128x32 = 512 chunks (2/thread)
    const int ga  = (tid >> 2) * IN_F + (tid & 3) * 8;
    const int gb1 = ((tid + 256) >> 2) * IN_F + (tid & 3) * 8;

    const int lane = tid & 63;
    const int wv   = tid >> 6;
    const int wmi  = wv >> 1, wni = wv & 1;   // 2x2 wave grid: 32 rows x 64 cols
    const int lm   = lane & 15, kq = lane >> 4;

    floatx4 acc[2][4];
#pragma unroll
    for (int i = 0; i < 2; i++)
#pragma unroll
        for (int j = 0; j < 4; j++)
            acc[i][j] = (floatx4){0.f, 0.f, 0.f, 0.f};

    for (int k0 = 0; k0 < IN_F; k0 += 32) {
        GLOBAL_LOAD_LDS16(Ag + ga  + k0, &As[tid * 8]);
        GLOBAL_LOAD_LDS16(Bg + ga  + k0, &Bs[tid * 8]);
        GLOBAL_LOAD_LDS16(Bg + gb1 + k0, &Bs[(tid + 256) * 8]);
        __syncthreads();   // staging complete (barrier drains vmcnt)

        short8 a[2], bb[4];
#pragma unroll
        for (int mi = 0; mi < 2; mi++)
            a[mi] = *(const short8*)&As[(wmi * 32 + mi * 16 + lm) * 32 + kq * 8];
#pragma unroll
        for (int ni = 0; ni < 4; ni++)
            bb[ni] = *(const short8*)&Bs[(wni * 64 + ni * 16 + lm) * 32 + kq * 8];

#pragma unroll
        for (int mi = 0; mi < 2; mi++)
#pragma unroll
            for (int ni = 0; ni < 4; ni++)
                acc[mi][ni] = __builtin_amdgcn_mfma_f32_16x16x32_bf16(
                    a[mi], bb[ni], acc[mi][ni], 0, 0, 0);
        __syncthreads();   // reads done before next staging overwrites LDS
    }

    // epilogue: C/D layout col=lane&15, row=(lane>>4)*4+reg
#pragma unroll
    for (int ni = 0; ni < 4; ni++) {
        const int gcol = n0 + wni * 64 + ni * 16 + lm;
        const float bv = bmixed[b * OUT_F + gcol];
#pragma unroll
        for (int mi = 0; mi < 2; mi++) {
            const int grow = m0 + wmi * 32 + mi * 16 + kq * 4;
            float* op = out + ((size_t)b * A_SZ + grow) * OUT_F + gcol;
#pragma unroll
            for (int r = 0; r < 4; r++)
                op[(size_t)r * OUT_F] = acc[mi][ni][r] + bv;
        }
    }
}

extern "C" void kernel_launch(void* const* d_in, const int* in_sizes, int n_in,
                              void* d_out, int out_size, void* d_ws, size_t ws_size,
                              hipStream_t stream) {
    const float* x      = (const float*)d_in[0];  // [8,512,1024]
    const float* sp     = (const float*)d_in[1];  // [8,16]
    const float* weight = (const float*)d_in[2];  // [16,1024,1024]
    const float* bias   = (const float*)d_in[3];  // [16,1024]
    float* out = (float*)d_out;                   // [8,512,1024]

    // workspace layout: wm bf16 16MB | xbf bf16 8MB | bmixed fp32 32KB
    unsigned short* wm  = (unsigned short*)d_ws;
    unsigned short* xbf = wm + (size_t)B_SZ * OUT_F * IN_F;
    float* bmixed       = (float*)(xbf + (size_t)B_SZ * A_SZ * IN_F);

    selin_prep<<<5128, 256, 0, stream>>>(x, sp, weight, bias, wm, xbf, bmixed);
    selin_gemm<<<512, 256, 0, stream>>>(xbf, wm, bmixed, out);
}

// Round 3
// 131.596 us; speedup vs baseline: 1.0432x; 1.0410x over previous
//
#include <hip/hip_runtime.h>
#include <hip/hip_bf16.h>

// Problem: B=8, A=512, IN=OUT=1024, N_OPT=16, fp32 in/out.
// out[b,a,i] = sum_j (sum_n sp[b,n] W[n,i,j]) x[b,a,j] + sum_n sp[b,n] bias[n,i]
//
// Strategy: mix weights once (reads W 64MB exactly once), cast to bf16,
// then 8 batched MFMA GEMMs (C = X * Wm^T), bias folded into epilogue.
//
// R2->R3: gemm retiled 64x128/512blk -> 64x64/1024blk (4 blocks/CU) with
// b = bid%8 XCD swizzle so each XCD's working set (wm[b]+xbf[b] = 3MB) fits
// its private 4MB L2 -> staging served by L2 instead of LLC.

#define B_SZ 8
#define A_SZ 512
#define IN_F 1024
#define OUT_F 1024
#define N_OPT 16

typedef short short8 __attribute__((ext_vector_type(8)));
typedef float floatx4 __attribute__((ext_vector_type(4)));

__device__ __forceinline__ unsigned short f2bf(float f) {
    unsigned int u = __builtin_bit_cast(unsigned int, f);
    u += 0x7fffu + ((u >> 16) & 1u);   // RNE; inputs finite
    return (unsigned short)(u >> 16);
}

#define GLOBAL_LOAD_LDS16(g, l)                                                    \
    __builtin_amdgcn_global_load_lds(                                              \
        (const __attribute__((address_space(1))) void*)(g),                        \
        (__attribute__((address_space(3))) void*)(l), 16, 0, 0)

// ---------------------------------------------------------------------------
// Kernel 1: prep.
//   blocks [0,1024):    weight mixing -> bf16 wm [8][1024][1024]
//   blocks [1024,5120): x fp32 -> bf16 xbf [8][512][1024]
//   blocks [5120,5128): bias mixing -> fp32 bmixed [8][1024]
// ---------------------------------------------------------------------------
__global__ __launch_bounds__(256) void selin_prep(
    const float* __restrict__ x, const float* __restrict__ sp,
    const float* __restrict__ weight, const float* __restrict__ bias,
    unsigned short* __restrict__ wm, unsigned short* __restrict__ xbf,
    float* __restrict__ bmixed)
{
    const int bid = blockIdx.x;
    const int tid = threadIdx.x;

    if (bid < 1024) {
        __shared__ float sps[B_SZ * N_OPT];
        if (tid < B_SZ * N_OPT) sps[tid] = sp[tid];
        __syncthreads();
        const int e4 = bid * 256 + tid;              // float4 index into 1024x1024
        const float4* w4 = (const float4*)weight;
        float4 w[N_OPT];
#pragma unroll
        for (int n = 0; n < N_OPT; n++)
            w[n] = w4[(size_t)n * (IN_F * OUT_F / 4) + e4];
#pragma unroll
        for (int b = 0; b < B_SZ; b++) {
            float ax = 0.f, ay = 0.f, az = 0.f, aw = 0.f;
#pragma unroll
            for (int n = 0; n < N_OPT; n++) {
                float s = sps[b * N_OPT + n];
                ax += s * w[n].x; ay += s * w[n].y;
                az += s * w[n].z; aw += s * w[n].w;
            }
            ushort4 o = make_ushort4(f2bf(ax), f2bf(ay), f2bf(az), f2bf(aw));
            ((ushort4*)wm)[(size_t)b * (IN_F * OUT_F / 4) + e4] = o;
        }
    } else if (bid < 5120) {
        const int idx = (bid - 1024) * 256 + tid;    // float4 index, 1M total
        float4 v = ((const float4*)x)[idx];
        ((ushort4*)xbf)[idx] = make_ushort4(f2bf(v.x), f2bf(v.y), f2bf(v.z), f2bf(v.w));
    } else {
        __shared__ float sps[B_SZ * N_OPT];
        if (tid < B_SZ * N_OPT) sps[tid] = sp[tid];
        __syncthreads();
        const int idx = (bid - 5120) * 256 + tid;    // 0..2047 (float4 over 8x1024)
        const int b = idx >> 8, i4 = idx & 255;
        const float4* bias4 = (const float4*)bias;
        float ax = 0.f, ay = 0.f, az = 0.f, aw = 0.f;
#pragma unroll
        for (int n = 0; n < N_OPT; n++) {
            float s = sps[b * N_OPT + n];
            float4 v = bias4[n * 256 + i4];
            ax += s * v.x; ay += s * v.y; az += s * v.z; aw += s * v.w;
        }
        ((float4*)bmixed)[idx] = make_float4(ax, ay, az, aw);
    }
}

// ---------------------------------------------------------------------------
// Kernel 2: batched GEMM, C[b] = X[b] (512x1024) * Wm[b]^T (1024x1024) + bias.
// Tile 64x64, BK=32. 4 waves in 2x2; each wave 32x32 = 2x2 frags of
// 16x16x32 bf16 MFMA. Grid: 1024 blocks (4/CU); b = bid%8 (XCD locality:
// round-robin dispatch puts each batch's 3MB working set in one XCD's L2).
// ---------------------------------------------------------------------------
__global__ __launch_bounds__(256) void selin_gemm(
    const unsigned short* __restrict__ xbf, const unsigned short* __restrict__ wm,
    const float* __restrict__ bmixed, float* __restrict__ out)
{
    __shared__ __align__(16) unsigned short As[64 * 32];    // 4 KB
    __shared__ __align__(16) unsigned short Bs[64 * 32];    // 4 KB

    const int tid = threadIdx.x;
    const int bid = blockIdx.x;
    const int b   = bid & 7;          // XCD swizzle: same b -> same XCD
    const int t   = bid >> 3;         // 0..127
    const int mb  = t & 7;            // 8 m-blocks of 64 rows
    const int nb  = t >> 3;           // 16 n-blocks of 64 cols
    const int m0  = mb * 64, n0 = nb * 64;

    const unsigned short* Ag = xbf + ((size_t)b * A_SZ  + m0) * IN_F;
    const unsigned short* Bg = wm  + ((size_t)b * OUT_F + n0) * IN_F;

    // 64x32 bf16 tile = 4KB = 256 16B-chunks; one chunk per thread.
    const int ga = (tid >> 2) * IN_F + (tid & 3) * 8;   // + k0 at use

    const int lane = tid & 63;
    const int wv   = tid >> 6;
    const int wmi  = wv >> 1, wni = wv & 1;   // 2x2 wave grid: 32 rows x 32 cols
    const int lm   = lane & 15, kq = lane >> 4;

    floatx4 acc[2][2];
#pragma unroll
    for (int i = 0; i < 2; i++)
#pragma unroll
        for (int j = 0; j < 2; j++)
            acc[i][j] = (floatx4){0.f, 0.f, 0.f, 0.f};

    for (int k0 = 0; k0 < IN_F; k0 += 32) {
        GLOBAL_LOAD_LDS16(Ag + ga + k0, &As[tid * 8]);
        GLOBAL_LOAD_LDS16(Bg + ga + k0, &Bs[tid * 8]);
        __syncthreads();   // staging complete (barrier drains vmcnt)

        short8 a[2], bb[2];
#pragma unroll
        for (int mi = 0; mi < 2; mi++)
            a[mi] = *(const short8*)&As[(wmi * 32 + mi * 16 + lm) * 32 + kq * 8];
#pragma unroll
        for (int ni = 0; ni < 2; ni++)
            bb[ni] = *(const short8*)&Bs[(wni * 32 + ni * 16 + lm) * 32 + kq * 8];

#pragma unroll
        for (int mi = 0; mi < 2; mi++)
#pragma unroll
            for (int ni = 0; ni < 2; ni++)
                acc[mi][ni] = __builtin_amdgcn_mfma_f32_16x16x32_bf16(
                    a[mi], bb[ni], acc[mi][ni], 0, 0, 0);
        __syncthreads();   // reads done before next staging overwrites LDS
    }

    // epilogue: C/D layout col=lane&15, row=(lane>>4)*4+reg
#pragma unroll
    for (int ni = 0; ni < 2; ni++) {
        const int gcol = n0 + wni * 32 + ni * 16 + lm;
        const float bv = bmixed[b * OUT_F + gcol];
#pragma unroll
        for (int mi = 0; mi < 2; mi++) {
            const int grow = m0 + wmi * 32 + mi * 16 + kq * 4;
            float* op = out + ((size_t)b * A_SZ + grow) * OUT_F + gcol;
#pragma unroll
            for (int r = 0; r < 4; r++)
                op[(size_t)r * OUT_F] = acc[mi][ni][r] + bv;
        }
    }
}

extern "C" void kernel_launch(void* const* d_in, const int* in_sizes, int n_in,
                              void* d_out, int out_size, void* d_ws, size_t ws_size,
                              hipStream_t stream) {
    const float* x      = (const float*)d_in[0];  // [8,512,1024]
    const float* sp     = (const float*)d_in[1];  // [8,16]
    const float* weight = (const float*)d_in[2];  // [16,1024,1024]
    const float* bias   = (const float*)d_in[3];  // [16,1024]
    float* out = (float*)d_out;                   // [8,512,1024]

    // workspace layout: wm bf16 16MB | xbf bf16 8MB | bmixed fp32 32KB
    unsigned short* wm  = (unsigned short*)d_ws;
    unsigned short* xbf = wm + (size_t)B_SZ * OUT_F * IN_F;
    float* bmixed       = (float*)(xbf + (size_t)B_SZ * A_SZ * IN_F);

    selin_prep<<<5128, 256, 0, stream>>>(x, sp, weight, bias, wm, xbf, bmixed);
    selin_gemm<<<1024, 256, 0, stream>>>(xbf, wm, bmixed, out);
}